// Round 8
// baseline (126.658 us; speedup 1.0000x reference)
//
#include <hip/hip_runtime.h>
#include <stdint.h>

#define NB 4
#define NN 512
#define NC 64
#define NH 128
#define NCO 64
#define MAXM 64          // fast-path cap on valid count
#define FBIG 3.0e38f

// mask dtype decode: int32 (w0==1), float32 (w0==0x3f800000), else packed bytes.
__device__ inline bool read_mask(const void* mp, int idx) {
    const int* ip = (const int*)mp;
    int w0 = ip[0];
    if (w0 == 1) return ip[idx] != 0;
    if (w0 == 0x3f800000) return ((const float*)mp)[idx] != 0.0f;
    return ((const unsigned char*)mp)[idx] != 0;
}

// One wave per row: neighbor census -> validbits = neighbors surviving row i's
// own dilation removal (self excluded). valid(i,j) = vb_i[j] && vb_j[i].
// Blocks 0..63 also transpose W1/W2.
__global__ __launch_bounds__(256) void prep_kernel(
        const float* __restrict__ adj, const void* __restrict__ maskp,
        const float* __restrict__ W1, const float* __restrict__ W2,
        uint64_t* __restrict__ validbits, float* __restrict__ W1T,
        float* __restrict__ W2T, int dowt)
{
    int wave = (blockIdx.x * 256 + threadIdx.x) >> 6;
    int lane = threadIdx.x & 63;
    if (wave < NB * NN) {
        int i = wave & (NN - 1);
        const float* arow = adj + (size_t)wave * NN;
        uint64_t ball[8];
        int m = 0;
        #pragma unroll
        for (int k = 0; k < 8; ++k) {
            int j = k * 64 + lane;
            bool f = (j != i) && (arow[j] > 0.0f);
            uint64_t bl = __ballot(f);
            ball[k] = bl;
            m += __popcll(bl);
        }
        int skip = (m > 10) ? ((m + 1) >> 1) : 1;   // ceil(m/2), K_DIL=2
        bool dodil = (skip > 1) && read_mask(maskp, wave);
        int skip2 = skip * 2;
        int prefix = 0;
        #pragma unroll
        for (int k = 0; k < 8; ++k) {
            uint64_t bl = ball[k];
            int rank1 = prefix + __popcll(bl & ((1ull << lane) - 1ull)) + 1;
            bool f = (bl >> lane) & 1ull;
            // (rank % skip)==0 <=> rank==skip || rank==2*skip  (rank <= m <= 2*skip)
            bool keep = f && !(dodil && (rank1 == skip || rank1 == skip2));
            uint64_t vb = __ballot(keep);
            if (lane == 0) validbits[(size_t)wave * 8 + k] = vb;
            prefix += __popcll(bl);
        }
    }
    if (dowt) {
        int e = blockIdx.x * 256 + threadIdx.x;
        if (e < 8192) {                       // W1T[k][c] = W1[c][k]
            int k = e >> 6, c = e & 63;
            W1T[e] = W1[c * NH + k];
        } else if (e < 16384) {               // W2T[o][k] = W2[k][o]
            int e2 = e - 8192;
            int o = e2 >> 7, k = e2 & 127;
            W2T[e2] = W2[k * NCO + o];
        }
    }
}

// ---- 4-elem/lane bitonic sort machinery. Element e = g*4 + r. ----
__device__ inline void cmpsw(float& a, float& b, bool asc) {
    float lo = fminf(a, b), hi = fmaxf(a, b);
    a = asc ? lo : hi;
    b = asc ? hi : lo;
}
__device__ inline void xstage(float q[4], int g, int ld, bool asc) {
    #pragma unroll
    for (int r = 0; r < 4; ++r) {
        float vp = __shfl_xor(q[r], ld);
        bool mn = ((g & ld) == 0) == asc;
        q[r] = mn ? fminf(q[r], vp) : fmaxf(q[r], vp);
    }
}
__device__ inline void regstages(float q[4], bool a) {  // d=2 then d=1
    cmpsw(q[0], q[2], a); cmpsw(q[1], q[3], a);
    cmpsw(q[0], q[1], a); cmpsw(q[2], q[3], a);
}
// Sort 64 elems ascending across a 16-lane group (g = lane&15), 4/lane.
__device__ inline void sort64_4(float q[4], int g) {
    cmpsw(q[0], q[1], true);  cmpsw(q[2], q[3], false);            // k=2
    regstages(q, (g & 1) == 0);                                    // k=4
    { bool a = (g & 2) == 0; xstage(q, g, 1, a); regstages(q, a); }// k=8
    { bool a = (g & 4) == 0; xstage(q, g, 2, a); xstage(q, g, 1, a);
      regstages(q, a); }                                           // k=16
    { bool a = (g & 8) == 0; xstage(q, g, 4, a); xstage(q, g, 2, a);
      xstage(q, g, 1, a); regstages(q, a); }                       // k=32
    { xstage(q, g, 8, true); xstage(q, g, 4, true); xstage(q, g, 2, true);
      xstage(q, g, 1, true); regstages(q, true); }                 // k=64
}
// Sort 32 elems ascending across an 8-lane group (g = lane&7), 4/lane.
__device__ inline void sort32_4(float q[4], int g) {
    cmpsw(q[0], q[1], true);  cmpsw(q[2], q[3], false);            // k=2
    regstages(q, (g & 1) == 0);                                    // k=4
    { bool a = (g & 2) == 0; xstage(q, g, 1, a); regstages(q, a); }// k=8
    { bool a = (g & 4) == 0; xstage(q, g, 2, a); xstage(q, g, 1, a);
      regstages(q, a); }                                           // k=16
    { xstage(q, g, 4, true); xstage(q, g, 2, true); xstage(q, g, 1, true);
      regstages(q, true); }                                        // k=32
}
__device__ inline float selreg(const float q[4], int r) {  // r wave-uniform
    float v = q[0];
    v = (r == 1) ? q[1] : v;
    v = (r == 2) ? q[2] : v;
    v = (r == 3) ? q[3] : v;
    return v;
}

// One 256-thread block per row. Valid list via precomputed validbits; values
// loaded straight into sort layout (x is L2-resident; no LDS staging);
// register-bitonic sort (4 elems/lane) for quantiles; fused GIN MLP.
template<bool USE_WT>
__global__ void fused_kernel(
        const float* __restrict__ x,
        const void* __restrict__ maskp,
        const float* __restrict__ W1,
        const float* __restrict__ b1,
        const float* __restrict__ W2,
        const float* __restrict__ b2,
        const uint64_t* __restrict__ validbits,
        const float* __restrict__ W1T,
        const float* __restrict__ W2T,
        float* __restrict__ out)
{
    int row = blockIdx.x;                // b*NN + i
    int b = row >> 9, i = row & (NN - 1);
    int tid = threadIdx.x, lane = tid & 63, wv = tid >> 6;
    float* outp = out + (size_t)row * NCO;

    if (!read_mask(maskp, row)) {        // masked row: explicit zeros (out poisoned)
        if (tid < NCO) outp[tid] = 0.0f;
        return;
    }

    __shared__ __align__(8) uint16_t s_idx[MAXM];  // valid list (unordered)
    __shared__ uint64_t s_vb[8];         // row i's validbits (no self)
    __shared__ uint64_t s_vf[8];         // full pairwise-valid bits (w/ self)
    __shared__ float s_agg[NC];          // per-channel weighted-quantile sum
    __shared__ float s_out[NC];
    __shared__ float s_h[NH];
    __shared__ float s_hp[2 * NH];
    __shared__ float s_part[4 * NCO];
    __shared__ int s_cnt;

    float xval = (tid < NC) ? x[(size_t)row * NC + tid] : 0.0f;  // prefetch
    if (tid < 8) s_vb[tid] = validbits[(size_t)row * 8 + tid];
    if (tid < MAXM) s_idx[tid] = (uint16_t)i;    // safe-address padding; slot 0=self
    if (tid == 0) s_cnt = 1;
    __syncthreads();

    // ---- P2: valid(i,j) = vb_i[j] && vb_j[i]; list append + full-valid ballot ----
    int ic = i >> 6;
    uint64_t imask = 1ull << (i & 63);
    #pragma unroll
    for (int it = 0; it < 2; ++it) {
        int j = tid + it * 256;
        bool nb = ((s_vb[j >> 6] >> (j & 63)) & 1ull) &&
                  (validbits[((size_t)(b * NN + j)) * 8 + ic] & imask);
        uint64_t bl = __ballot(nb || (j == i));
        if (lane == 0) s_vf[it * 4 + wv] = bl;
        if (nb) {
            int p = atomicAdd(&s_cnt, 1);
            if (p < MAXM) s_idx[p] = (uint16_t)j;
        }
    }
    __syncthreads();
    int m = s_cnt;                       // >= 1 (self-loop)

    // ---- quantile positions (torch 'linear') ----
    float mf = (float)m;
    const float taus[3] = {0.25f, 0.5f, 0.75f};
    const float wts[3]  = {0.25f, 0.5f, 0.25f};
    int tlo[3], thi[3];
    float tfrac[3];
    #pragma unroll
    for (int t = 0; t < 3; ++t) {
        float pos = taus[t] * (mf - 1.0f);
        float fl = floorf(pos);
        tlo[t] = (int)fl;
        thi[t] = (int)ceilf(pos);
        tfrac[t] = pos - fl;
    }

    const float* xb = x + (size_t)b * NN * NC;

    if (m <= 32) {
        // 8-lane groups, 8 channels/wave/pass, 2 passes
        int g = lane & 7, sg = lane >> 3;
        ushort4 id4 = ((const ushort4*)s_idx)[g];
        int j0 = g * 4;
        #pragma unroll
        for (int p = 0; p < 2; ++p) {
            int c = p * 32 + wv * 8 + sg;
            float q[4];
            q[0] = (j0 + 0 < m) ? xb[(int)id4.x * NC + c] : FBIG;
            q[1] = (j0 + 1 < m) ? xb[(int)id4.y * NC + c] : FBIG;
            q[2] = (j0 + 2 < m) ? xb[(int)id4.z * NC + c] : FBIG;
            q[3] = (j0 + 3 < m) ? xb[(int)id4.w * NC + c] : FBIG;
            sort32_4(q, g);
            float agg = 0.0f;
            #pragma unroll
            for (int t = 0; t < 3; ++t) {
                float sl = selreg(q, tlo[t] & 3);
                float vlo = __shfl(sl, (lane & 56) | (tlo[t] >> 2));
                float sh = selreg(q, thi[t] & 3);
                float vhi = __shfl(sh, (lane & 56) | (thi[t] >> 2));
                agg += wts[t] * (vlo * (1.0f - tfrac[t]) + vhi * tfrac[t]);
            }
            if (g == 0) s_agg[c] = agg;
        }
    } else if (m <= MAXM) {
        // 16-lane groups, 4 channels/wave/pass, 4 passes
        int g = lane & 15, sg = lane >> 4;
        ushort4 id4 = ((const ushort4*)s_idx)[g];
        int j0 = g * 4;
        #pragma unroll
        for (int p = 0; p < 4; ++p) {
            int c = p * 16 + wv * 4 + sg;
            float q[4];
            q[0] = (j0 + 0 < m) ? xb[(int)id4.x * NC + c] : FBIG;
            q[1] = (j0 + 1 < m) ? xb[(int)id4.y * NC + c] : FBIG;
            q[2] = (j0 + 2 < m) ? xb[(int)id4.z * NC + c] : FBIG;
            q[3] = (j0 + 3 < m) ? xb[(int)id4.w * NC + c] : FBIG;
            sort64_4(q, g);
            float agg = 0.0f;
            #pragma unroll
            for (int t = 0; t < 3; ++t) {
                float sl = selreg(q, tlo[t] & 3);
                float vlo = __shfl(sl, (lane & 48) | (tlo[t] >> 2));
                float sh = selreg(q, thi[t] & 3);
                float vhi = __shfl(sh, (lane & 48) | (thi[t] >> 2));
                agg += wts[t] * (vlo * (1.0f - tfrac[t]) + vhi * tfrac[t]);
            }
            if (g == 0) s_agg[c] = agg;
        }
    } else {
        // correctness-only fallback (m > 64; never triggers on bench data)
        if (tid < NC) {
            int c = tid;
            float qv[6];
            for (int j1 = 0; j1 < NN; ++j1) {
                if (!((s_vf[j1 >> 6] >> (j1 & 63)) & 1ull)) continue;
                float v1 = xb[j1 * NC + c];
                int rs = 0, rl = 0;
                for (int j2 = 0; j2 < NN; ++j2) {
                    if (!((s_vf[j2 >> 6] >> (j2 & 63)) & 1ull)) continue;
                    float v2 = xb[j2 * NC + c];
                    rs += v2 < v1;
                    rl += v2 <= v1;
                }
                #pragma unroll
                for (int t = 0; t < 3; ++t) {
                    if (rs <= tlo[t] && tlo[t] < rl) qv[2 * t]     = v1;
                    if (rs <= thi[t] && thi[t] < rl) qv[2 * t + 1] = v1;
                }
            }
            float agg = 0.0f;
            #pragma unroll
            for (int t = 0; t < 3; ++t)
                agg += wts[t] * (qv[2 * t] * (1.0f - tfrac[t]) + qv[2 * t + 1] * tfrac[t]);
            s_agg[c] = agg;
        }
    }
    __syncthreads();

    if (tid < NC)                        // out = x + weighted-quantile agg
        s_out[tid] = xval + s_agg[tid];
    __syncthreads();

    // ---- MLP1: 256 threads = 128 k x 2 cc-halves ----
    {
        int k = tid & 127, g = tid >> 7;
        float acc = 0.0f;
        if (USE_WT) {
            const float4* w = (const float4*)(W1T + k * 64 + g * 32);
            #pragma unroll
            for (int q = 0; q < 8; ++q) {
                float4 wq = w[q];
                int cc = g * 32 + q * 4;
                acc += wq.x * s_out[cc] + wq.y * s_out[cc + 1]
                     + wq.z * s_out[cc + 2] + wq.w * s_out[cc + 3];
            }
        } else {
            for (int cc = g * 32; cc < g * 32 + 32; ++cc)
                acc += s_out[cc] * W1[cc * NH + k];
        }
        s_hp[g * NH + k] = acc;
    }
    __syncthreads();
    if (tid < NH) {
        float a = s_hp[tid] + s_hp[NH + tid] + b1[tid];
        s_h[tid] = a > 0.0f ? a : 0.0f;
    }
    __syncthreads();

    // ---- MLP2: 256 threads = 64 o x 4 k-quarters ----
    {
        int o = tid & 63, g = tid >> 6;
        float acc = 0.0f;
        if (USE_WT) {
            const float4* w = (const float4*)(W2T + o * 128 + g * 32);
            #pragma unroll
            for (int q = 0; q < 8; ++q) {
                float4 wq = w[q];
                int k = g * 32 + q * 4;
                acc += wq.x * s_h[k] + wq.y * s_h[k + 1]
                     + wq.z * s_h[k + 2] + wq.w * s_h[k + 3];
            }
        } else {
            for (int k = g * 32; k < g * 32 + 32; ++k)
                acc += s_h[k] * W2[k * NCO + o];
        }
        s_part[g * NCO + o] = acc;
    }
    __syncthreads();
    if (tid < NCO)
        outp[tid] = s_part[tid] + s_part[64 + tid] + s_part[128 + tid]
                  + s_part[192 + tid] + b2[tid];
}

extern "C" void kernel_launch(void* const* d_in, const int* in_sizes, int n_in,
                              void* d_out, int out_size, void* d_ws, size_t ws_size,
                              hipStream_t stream) {
    const float* x   = (const float*)d_in[0];
    const float* adj = (const float*)d_in[1];
    const void* mask = d_in[2];
    const float* W1  = (const float*)d_in[3];
    const float* b1  = (const float*)d_in[4];
    const float* W2  = (const float*)d_in[5];
    const float* b2  = (const float*)d_in[6];
    float* out = (float*)d_out;

    uint64_t* validbits = (uint64_t*)d_ws;               // 128 KB
    float* W1T = (float*)((char*)d_ws + 131072);         // 32 KB
    float* W2T = W1T + 8192;                             // 32 KB
    int dowt = (ws_size >= 196608) ? 1 : 0;

    prep_kernel<<<512, 256, 0, stream>>>(adj, mask, W1, W2, validbits, W1T, W2T, dowt);
    if (dowt)
        fused_kernel<true><<<NB * NN, 256, 0, stream>>>(
            x, mask, W1, b1, W2, b2, validbits, W1T, W2T, out);
    else
        fused_kernel<false><<<NB * NN, 256, 0, stream>>>(
            x, mask, W1, b1, W2, b2, validbits, W1T, W2T, out);
}

// Round 9
// 110.241 us; speedup vs baseline: 1.1489x; 1.1489x over previous
//
#include <hip/hip_runtime.h>
#include <stdint.h>

#define NB 4
#define NN 512
#define NC 64
#define NH 128
#define NCO 64
#define MAXM 64          // fast-path cap on valid count
#define FBIG 3.0e38f

// mask dtype decode: int32 (w0==1), float32 (w0==0x3f800000), else packed bytes.
__device__ inline bool read_mask(const void* mp, int idx) {
    const int* ip = (const int*)mp;
    int w0 = ip[0];
    if (w0 == 1) return ip[idx] != 0;
    if (w0 == 0x3f800000) return ((const float*)mp)[idx] != 0.0f;
    return ((const unsigned char*)mp)[idx] != 0;
}

// One wave per row: neighbor census -> validbits = neighbors surviving row i's
// own dilation removal (self excluded). valid(i,j) = vb_i[j] && vb_j[i].
// Blocks 0..63 also transpose W1/W2.
__global__ __launch_bounds__(256) void prep_kernel(
        const float* __restrict__ adj, const void* __restrict__ maskp,
        const float* __restrict__ W1, const float* __restrict__ W2,
        uint64_t* __restrict__ validbits, float* __restrict__ W1T,
        float* __restrict__ W2T, int dowt)
{
    int wave = (blockIdx.x * 256 + threadIdx.x) >> 6;
    int lane = threadIdx.x & 63;
    if (wave < NB * NN) {
        int i = wave & (NN - 1);
        const float* arow = adj + (size_t)wave * NN;
        uint64_t ball[8];
        int m = 0;
        #pragma unroll
        for (int k = 0; k < 8; ++k) {
            int j = k * 64 + lane;
            bool f = (j != i) && (arow[j] > 0.0f);
            uint64_t bl = __ballot(f);
            ball[k] = bl;
            m += __popcll(bl);
        }
        int skip = (m > 10) ? ((m + 1) >> 1) : 1;   // ceil(m/2), K_DIL=2
        bool dodil = (skip > 1) && read_mask(maskp, wave);
        int skip2 = skip * 2;
        int prefix = 0;
        #pragma unroll
        for (int k = 0; k < 8; ++k) {
            uint64_t bl = ball[k];
            int rank1 = prefix + __popcll(bl & ((1ull << lane) - 1ull)) + 1;
            bool f = (bl >> lane) & 1ull;
            // (rank % skip)==0 <=> rank==skip || rank==2*skip  (rank <= m <= 2*skip)
            bool keep = f && !(dodil && (rank1 == skip || rank1 == skip2));
            uint64_t vb = __ballot(keep);
            if (lane == 0) validbits[(size_t)wave * 8 + k] = vb;
            prefix += __popcll(bl);
        }
    }
    if (dowt) {
        int e = blockIdx.x * 256 + threadIdx.x;
        if (e < 8192) {                       // W1T[k][c] = W1[c][k]
            int k = e >> 6, c = e & 63;
            W1T[e] = W1[c * NH + k];
        } else if (e < 16384) {               // W2T[o][k] = W2[k][o]
            int e2 = e - 8192;
            int o = e2 >> 7, k = e2 & 127;
            W2T[e2] = W2[k * NCO + o];
        }
    }
}

// ---- 4-elem/lane bitonic sort machinery. Element e = g*4 + r. ----
__device__ __forceinline__ void cmpsw(float& a, float& b, bool asc) {
    float lo = fminf(a, b), hi = fmaxf(a, b);
    a = asc ? lo : hi;
    b = asc ? hi : lo;
}
__device__ __forceinline__ void xstage(float q[4], int g, int ld, bool asc) {
    #pragma unroll
    for (int r = 0; r < 4; ++r) {
        float vp = __shfl_xor(q[r], ld);
        bool mn = ((g & ld) == 0) == asc;
        q[r] = mn ? fminf(q[r], vp) : fmaxf(q[r], vp);
    }
}
__device__ __forceinline__ void regstages(float q[4], bool a) {  // d=2 then d=1
    cmpsw(q[0], q[2], a); cmpsw(q[1], q[3], a);
    cmpsw(q[0], q[1], a); cmpsw(q[2], q[3], a);
}
// Sort 64 elems ascending across a 16-lane group (g = lane&15), 4/lane.
__device__ __forceinline__ void sort64_4(float q[4], int g) {
    cmpsw(q[0], q[1], true);  cmpsw(q[2], q[3], false);            // k=2
    regstages(q, (g & 1) == 0);                                    // k=4
    { bool a = (g & 2) == 0; xstage(q, g, 1, a); regstages(q, a); }// k=8
    { bool a = (g & 4) == 0; xstage(q, g, 2, a); xstage(q, g, 1, a);
      regstages(q, a); }                                           // k=16
    { bool a = (g & 8) == 0; xstage(q, g, 4, a); xstage(q, g, 2, a);
      xstage(q, g, 1, a); regstages(q, a); }                       // k=32
    { xstage(q, g, 8, true); xstage(q, g, 4, true); xstage(q, g, 2, true);
      xstage(q, g, 1, true); regstages(q, true); }                 // k=64
}
// Sort 32 elems ascending across an 8-lane group (g = lane&7), 4/lane.
__device__ __forceinline__ void sort32_4(float q[4], int g) {
    cmpsw(q[0], q[1], true);  cmpsw(q[2], q[3], false);            // k=2
    regstages(q, (g & 1) == 0);                                    // k=4
    { bool a = (g & 2) == 0; xstage(q, g, 1, a); regstages(q, a); }// k=8
    { bool a = (g & 4) == 0; xstage(q, g, 2, a); xstage(q, g, 1, a);
      regstages(q, a); }                                           // k=16
    { xstage(q, g, 4, true); xstage(q, g, 2, true); xstage(q, g, 1, true);
      regstages(q, true); }                                        // k=32
}
__device__ __forceinline__ float selreg(const float q[4], int r) {  // r wave-uniform
    float v = q[0];
    v = (r == 1) ? q[1] : v;
    v = (r == 2) ? q[2] : v;
    v = (r == 3) ? q[3] : v;
    return v;
}

// One 256-thread block per row. Valid list via precomputed validbits; values
// loaded straight into sort layout (x is L2-resident; no LDS staging);
// register-bitonic sort (4 elems/lane) for quantiles; fused GIN MLP.
// launch_bounds(256,4) = 128-VGPR budget: REQUIRED. Without it the gfx950
// compiler caps at 32 VGPRs and demotes the sort arrays to LDS (round 8:
// LDS_Block_Size ballooned 3.3K->36K, kernel regressed 50->58 µs).
template<bool USE_WT>
__global__ __launch_bounds__(256, 4) void fused_kernel(
        const float* __restrict__ x,
        const void* __restrict__ maskp,
        const float* __restrict__ W1,
        const float* __restrict__ b1,
        const float* __restrict__ W2,
        const float* __restrict__ b2,
        const uint64_t* __restrict__ validbits,
        const float* __restrict__ W1T,
        const float* __restrict__ W2T,
        float* __restrict__ out)
{
    int row = blockIdx.x;                // b*NN + i
    int b = row >> 9, i = row & (NN - 1);
    int tid = threadIdx.x, lane = tid & 63, wv = tid >> 6;
    float* outp = out + (size_t)row * NCO;

    if (!read_mask(maskp, row)) {        // masked row: explicit zeros (out poisoned)
        if (tid < NCO) outp[tid] = 0.0f;
        return;
    }

    __shared__ __align__(8) uint16_t s_idx[MAXM];  // valid list (unordered)
    __shared__ uint64_t s_vb[8];         // row i's validbits (no self)
    __shared__ uint64_t s_vf[8];         // full pairwise-valid bits (w/ self)
    __shared__ float s_agg[NC];          // per-channel weighted-quantile sum
    __shared__ float s_out[NC];
    __shared__ float s_h[NH];
    __shared__ float s_hp[2 * NH];
    __shared__ float s_part[4 * NCO];
    __shared__ int s_cnt;

    float xval = (tid < NC) ? x[(size_t)row * NC + tid] : 0.0f;  // prefetch
    if (tid < 8) s_vb[tid] = validbits[(size_t)row * 8 + tid];
    if (tid < MAXM) s_idx[tid] = (uint16_t)i;    // safe-address padding; slot 0=self
    if (tid == 0) s_cnt = 1;
    __syncthreads();

    // ---- P2: valid(i,j) = vb_i[j] && vb_j[i]; list append + full-valid ballot ----
    int ic = i >> 6;
    uint64_t imask = 1ull << (i & 63);
    #pragma unroll
    for (int it = 0; it < 2; ++it) {
        int j = tid + it * 256;
        bool nb = ((s_vb[j >> 6] >> (j & 63)) & 1ull) &&
                  (validbits[((size_t)(b * NN + j)) * 8 + ic] & imask);
        uint64_t bl = __ballot(nb || (j == i));
        if (lane == 0) s_vf[it * 4 + wv] = bl;
        if (nb) {
            int p = atomicAdd(&s_cnt, 1);
            if (p < MAXM) s_idx[p] = (uint16_t)j;
        }
    }
    __syncthreads();
    int m = s_cnt;                       // >= 1 (self-loop)

    // ---- quantile positions (torch 'linear') ----
    float mf = (float)m;
    const float taus[3] = {0.25f, 0.5f, 0.75f};
    const float wts[3]  = {0.25f, 0.5f, 0.25f};
    int tlo[3], thi[3];
    float tfrac[3];
    #pragma unroll
    for (int t = 0; t < 3; ++t) {
        float pos = taus[t] * (mf - 1.0f);
        float fl = floorf(pos);
        tlo[t] = (int)fl;
        thi[t] = (int)ceilf(pos);
        tfrac[t] = pos - fl;
    }

    const float* xb = x + (size_t)b * NN * NC;

    if (m <= 32) {
        // 8-lane groups, 8 channels/wave/pass, 2 passes
        int g = lane & 7, sg = lane >> 3;
        ushort4 id4 = ((const ushort4*)s_idx)[g];
        int j0 = g * 4;
        #pragma unroll
        for (int p = 0; p < 2; ++p) {
            int c = p * 32 + wv * 8 + sg;
            float q[4];
            q[0] = (j0 + 0 < m) ? xb[(int)id4.x * NC + c] : FBIG;
            q[1] = (j0 + 1 < m) ? xb[(int)id4.y * NC + c] : FBIG;
            q[2] = (j0 + 2 < m) ? xb[(int)id4.z * NC + c] : FBIG;
            q[3] = (j0 + 3 < m) ? xb[(int)id4.w * NC + c] : FBIG;
            sort32_4(q, g);
            float agg = 0.0f;
            #pragma unroll
            for (int t = 0; t < 3; ++t) {
                float sl = selreg(q, tlo[t] & 3);
                float vlo = __shfl(sl, (lane & 56) | (tlo[t] >> 2));
                float sh = selreg(q, thi[t] & 3);
                float vhi = __shfl(sh, (lane & 56) | (thi[t] >> 2));
                agg += wts[t] * (vlo * (1.0f - tfrac[t]) + vhi * tfrac[t]);
            }
            if (g == 0) s_agg[c] = agg;
        }
    } else if (m <= MAXM) {
        // 16-lane groups, 4 channels/wave/pass, 4 passes
        int g = lane & 15, sg = lane >> 4;
        ushort4 id4 = ((const ushort4*)s_idx)[g];
        int j0 = g * 4;
        #pragma unroll
        for (int p = 0; p < 4; ++p) {
            int c = p * 16 + wv * 4 + sg;
            float q[4];
            q[0] = (j0 + 0 < m) ? xb[(int)id4.x * NC + c] : FBIG;
            q[1] = (j0 + 1 < m) ? xb[(int)id4.y * NC + c] : FBIG;
            q[2] = (j0 + 2 < m) ? xb[(int)id4.z * NC + c] : FBIG;
            q[3] = (j0 + 3 < m) ? xb[(int)id4.w * NC + c] : FBIG;
            sort64_4(q, g);
            float agg = 0.0f;
            #pragma unroll
            for (int t = 0; t < 3; ++t) {
                float sl = selreg(q, tlo[t] & 3);
                float vlo = __shfl(sl, (lane & 48) | (tlo[t] >> 2));
                float sh = selreg(q, thi[t] & 3);
                float vhi = __shfl(sh, (lane & 48) | (thi[t] >> 2));
                agg += wts[t] * (vlo * (1.0f - tfrac[t]) + vhi * tfrac[t]);
            }
            if (g == 0) s_agg[c] = agg;
        }
    } else {
        // correctness-only fallback (m > 64; never triggers on bench data)
        if (tid < NC) {
            int c = tid;
            float qv[6];
            for (int j1 = 0; j1 < NN; ++j1) {
                if (!((s_vf[j1 >> 6] >> (j1 & 63)) & 1ull)) continue;
                float v1 = xb[j1 * NC + c];
                int rs = 0, rl = 0;
                for (int j2 = 0; j2 < NN; ++j2) {
                    if (!((s_vf[j2 >> 6] >> (j2 & 63)) & 1ull)) continue;
                    float v2 = xb[j2 * NC + c];
                    rs += v2 < v1;
                    rl += v2 <= v1;
                }
                #pragma unroll
                for (int t = 0; t < 3; ++t) {
                    if (rs <= tlo[t] && tlo[t] < rl) qv[2 * t]     = v1;
                    if (rs <= thi[t] && thi[t] < rl) qv[2 * t + 1] = v1;
                }
            }
            float agg = 0.0f;
            #pragma unroll
            for (int t = 0; t < 3; ++t)
                agg += wts[t] * (qv[2 * t] * (1.0f - tfrac[t]) + qv[2 * t + 1] * tfrac[t]);
            s_agg[c] = agg;
        }
    }
    __syncthreads();

    if (tid < NC)                        // out = x + weighted-quantile agg
        s_out[tid] = xval + s_agg[tid];
    __syncthreads();

    // ---- MLP1: 256 threads = 128 k x 2 cc-halves ----
    {
        int k = tid & 127, g = tid >> 7;
        float acc = 0.0f;
        if (USE_WT) {
            const float4* w = (const float4*)(W1T + k * 64 + g * 32);
            #pragma unroll
            for (int q = 0; q < 8; ++q) {
                float4 wq = w[q];
                int cc = g * 32 + q * 4;
                acc += wq.x * s_out[cc] + wq.y * s_out[cc + 1]
                     + wq.z * s_out[cc + 2] + wq.w * s_out[cc + 3];
            }
        } else {
            for (int cc = g * 32; cc < g * 32 + 32; ++cc)
                acc += s_out[cc] * W1[cc * NH + k];
        }
        s_hp[g * NH + k] = acc;
    }
    __syncthreads();
    if (tid < NH) {
        float a = s_hp[tid] + s_hp[NH + tid] + b1[tid];
        s_h[tid] = a > 0.0f ? a : 0.0f;
    }
    __syncthreads();

    // ---- MLP2: 256 threads = 64 o x 4 k-quarters ----
    {
        int o = tid & 63, g = tid >> 6;
        float acc = 0.0f;
        if (USE_WT) {
            const float4* w = (const float4*)(W2T + o * 128 + g * 32);
            #pragma unroll
            for (int q = 0; q < 8; ++q) {
                float4 wq = w[q];
                int k = g * 32 + q * 4;
                acc += wq.x * s_h[k] + wq.y * s_h[k + 1]
                     + wq.z * s_h[k + 2] + wq.w * s_h[k + 3];
            }
        } else {
            for (int k = g * 32; k < g * 32 + 32; ++k)
                acc += s_h[k] * W2[k * NCO + o];
        }
        s_part[g * NCO + o] = acc;
    }
    __syncthreads();
    if (tid < NCO)
        outp[tid] = s_part[tid] + s_part[64 + tid] + s_part[128 + tid]
                  + s_part[192 + tid] + b2[tid];
}

extern "C" void kernel_launch(void* const* d_in, const int* in_sizes, int n_in,
                              void* d_out, int out_size, void* d_ws, size_t ws_size,
                              hipStream_t stream) {
    const float* x   = (const float*)d_in[0];
    const float* adj = (const float*)d_in[1];
    const void* mask = d_in[2];
    const float* W1  = (const float*)d_in[3];
    const float* b1  = (const float*)d_in[4];
    const float* W2  = (const float*)d_in[5];
    const float* b2  = (const float*)d_in[6];
    float* out = (float*)d_out;

    uint64_t* validbits = (uint64_t*)d_ws;               // 128 KB
    float* W1T = (float*)((char*)d_ws + 131072);         // 32 KB
    float* W2T = W1T + 8192;                             // 32 KB
    int dowt = (ws_size >= 196608) ? 1 : 0;

    prep_kernel<<<512, 256, 0, stream>>>(adj, mask, W1, W2, validbits, W1T, W2T, dowt);
    if (dowt)
        fused_kernel<true><<<NB * NN, 256, 0, stream>>>(
            x, mask, W1, b1, W2, b2, validbits, W1T, W2T, out);
    else
        fused_kernel<false><<<NB * NN, 256, 0, stream>>>(
            x, mask, W1, b1, W2, b2, validbits, W1T, W2T, out);
}